// Round 6
// baseline (110.999 us; speedup 1.0000x reference)
//
#include <hip/hip_runtime.h>
#include <hip/hip_bf16.h>

typedef float f32x4 __attribute__((ext_vector_type(4)));

#define M_DIM   500000
#define NPER    21
#define NELEM   (M_DIM * NPER)          // 10,500,000 floats per (tensor, group)
#define NBX     128
#define TPB     252
#define CHE     16                       // elements per thread-chunk (64 B contiguous)
#define PASS_E  (NBX * TPB * CHE)        // 516,096 elements per grid pass (= 21*24576)
#define DM      (PASS_E / 21)            // 24,576: m advance per pass
#define P_FULL  20                       // passes 0..19 fully in-bounds (20*516096 = 10,321,920)

__device__ __forceinline__ float sig_fast(float st, float k1, float k0) {
    // sigmoid(B*(base+st)) = 1/(1+2^(k1*st+k0)),  k1=-B*log2e, k0=k1*base
    return __builtin_amdgcn_rcpf(1.0f + __builtin_amdgcn_exp2f(fmaf(st, k1, k0)));
}

__global__ __launch_bounds__(TPB) void probs_reduce_kernel(
    const float* __restrict__ ST0, const float* __restrict__ W0,
    const float* __restrict__ ST1, const float* __restrict__ W1,
    const float* __restrict__ BEV, const float* __restrict__ BEVp,
    const float* __restrict__ Bp, float* __restrict__ partial)
{
    const int t   = threadIdx.x;
    const int tau = blockIdx.y >> 2;   // 0: (ST0,W0)  1: (ST1,W1)
    const int grp = blockIdx.y & 3;

    const float* __restrict__ ST = (tau == 0 ? ST0 : ST1) + grp * M_DIM;
    const float* __restrict__ Wg = (tau == 0 ? W0 : W1) + (size_t)grp * NELEM;

    const float B    = Bp[0];
    const float base = fmaxf(BEVp[0], 0.0f) * BEV[0];
    const float k1   = -B * 1.44269504f;
    const float k0   = k1 * base;

    int e0 = (blockIdx.x * TPB + t) * CHE;        // element index of this thread's 64B chunk
    int m  = (int)((unsigned)e0 / 21u);
    const int cthr = 21 - (e0 - m * 21);          // j < cthr -> sig(m), else sig(m+1); one boundary max

    float a0=0.f,a1=0.f,a2=0.f,a3=0.f,a4=0.f,a5=0.f,a6=0.f,a7=0.f;
    float a8=0.f,a9=0.f,a10=0.f,a11=0.f,a12=0.f,a13=0.f,a14=0.f,a15=0.f;

#define BODY()                                                          \
    {                                                                   \
        const f32x4* wp = (const f32x4*)(Wg + (size_t)e0);              \
        const f32x4 wA = __builtin_nontemporal_load(wp);                \
        const f32x4 wB = __builtin_nontemporal_load(wp + 1);            \
        const f32x4 wC = __builtin_nontemporal_load(wp + 2);            \
        const f32x4 wD = __builtin_nontemporal_load(wp + 3);            \
        const int   mp = (m + 1 < M_DIM) ? m + 1 : M_DIM - 1;           \
        const float g0 = sig_fast(ST[m],  k1, k0);                      \
        const float g1 = sig_fast(ST[mp], k1, k0);                      \
        a0  = fmaf(wA[0], g0, a0);                                      \
        a1  = fmaf(wA[1], ( 1 < cthr) ? g0 : g1, a1);                   \
        a2  = fmaf(wA[2], ( 2 < cthr) ? g0 : g1, a2);                   \
        a3  = fmaf(wA[3], ( 3 < cthr) ? g0 : g1, a3);                   \
        a4  = fmaf(wB[0], ( 4 < cthr) ? g0 : g1, a4);                   \
        a5  = fmaf(wB[1], ( 5 < cthr) ? g0 : g1, a5);                   \
        a6  = fmaf(wB[2], ( 6 < cthr) ? g0 : g1, a6);                   \
        a7  = fmaf(wB[3], ( 7 < cthr) ? g0 : g1, a7);                   \
        a8  = fmaf(wC[0], ( 8 < cthr) ? g0 : g1, a8);                   \
        a9  = fmaf(wC[1], ( 9 < cthr) ? g0 : g1, a9);                   \
        a10 = fmaf(wC[2], (10 < cthr) ? g0 : g1, a10);                  \
        a11 = fmaf(wC[3], (11 < cthr) ? g0 : g1, a11);                  \
        a12 = fmaf(wD[0], (12 < cthr) ? g0 : g1, a12);                  \
        a13 = fmaf(wD[1], (13 < cthr) ? g0 : g1, a13);                  \
        a14 = fmaf(wD[2], (14 < cthr) ? g0 : g1, a14);                  \
        a15 = fmaf(wD[3], (15 < cthr) ? g0 : g1, a15);                  \
    }

    #pragma unroll 1
    for (int p = 0; p < P_FULL; ++p) {
        BODY();
        e0 += PASS_E; m += DM;
    }
    if (e0 < NELEM) {                               // tail pass: chunk fully in or out
        BODY();
    }
#undef BODY

    // residue of element (t*16 + j) is (16t+j) % 21; block span 4032 % 21 == 0
    __shared__ float sm[TPB * CHE];                 // 16 KB
    float* row = &sm[t * CHE];
    row[0]=a0; row[1]=a1; row[2]=a2; row[3]=a3; row[4]=a4; row[5]=a5;
    row[6]=a6; row[7]=a7; row[8]=a8; row[9]=a9; row[10]=a10; row[11]=a11;
    row[12]=a12; row[13]=a13; row[14]=a14; row[15]=a15;
    __syncthreads();

    if (t < NPER) {
        float s = 0.f;
        #pragma unroll
        for (int q = 0; q < (TPB * CHE) / NPER; ++q)   // 192 entries per residue
            s += sm[t + NPER * q];
        partial[(blockIdx.y * NBX + blockIdx.x) * NPER + t] = s;   // no atomics, no memset
    }
}

__global__ __launch_bounds__(256) void probs_final_kernel(
    const float* __restrict__ partial,   // (8, NBX, 21)
    const float* __restrict__ pp,        // (5,4)
    float* __restrict__ out)
{
    __shared__ float tmpL[168];          // (8,21): y*21+p
    __shared__ float red[256];
    const int t = threadIdx.x;

    if (t < 168) {
        const int y = t / NPER, p = t % NPER;
        float s = 0.f;
        #pragma unroll 4
        for (int bx = 0; bx < NBX; ++bx)
            s += partial[(y * NBX + bx) * NPER + p];
        tmpL[y * NPER + p] = s;
    }
    __syncthreads();

    float val = 0.f;
    if (t < 84) {
        const int i = t / 21, inner = t % 21;
        float Pk[5];
        #pragma unroll
        for (int k = 0; k < 5; ++k) {
            float a0 = pp[k*4+0], a1 = pp[k*4+1], a2 = pp[k*4+2], a3 = pp[k*4+3];
            float mx = fmaxf(fmaxf(a0, a1), fmaxf(a2, a3));
            float e0 = __expf(a0-mx), e1 = __expf(a1-mx), e2 = __expf(a2-mx), e3 = __expf(a3-mx);
            float inv = 1.0f / (e0 + e1 + e2 + e3);
            float q[4] = {e0*inv, e1*inv, e2*inv, e3*inv};
            float v = q[i];
            if (inner > 0) {
                int jj = (inner - 1) / 5, kk = (inner - 1) % 5;
                v *= q[jj];
                if (kk > 0) v *= q[kk - 1];
            }
            Pk[k] = v;
        }
        float t0 = tmpL[t], t1 = tmpL[84 + t];
        val = Pk[0] * t0 + (Pk[1] + Pk[2] + Pk[3] + Pk[4]) * t1;
    }
    red[t] = val;
    __syncthreads();
    #pragma unroll
    for (int s = 128; s > 0; s >>= 1) {
        if (t < s) red[t] += red[t + s];
        __syncthreads();
    }
    if (t == 0) out[0] = red[0] * 0.2f;   // mean over 5 outs
}

extern "C" void kernel_launch(void* const* d_in, const int* in_sizes, int n_in,
                              void* d_out, int out_size, void* d_ws, size_t ws_size,
                              hipStream_t stream) {
    const float* BEV  = (const float*)d_in[0];
    const float* ST0  = (const float*)d_in[1];
    const float* W0   = (const float*)d_in[2];
    const float* ST1  = (const float*)d_in[3];
    const float* W1   = (const float*)d_in[4];
    const float* pp   = (const float*)d_in[5];
    const float* BEVp = (const float*)d_in[6];
    const float* B    = (const float*)d_in[7];
    float* out = (float*)d_out;
    float* partial = (float*)d_ws;   // 8*NBX*21 = 21,504 floats (86 KB), fully overwritten each call

    probs_reduce_kernel<<<dim3(NBX, 8), TPB, 0, stream>>>(ST0, W0, ST1, W1,
                                                          BEV, BEVp, B, partial);
    probs_final_kernel<<<1, 256, 0, stream>>>(partial, pp, out);
}

// Round 7
// 87.508 us; speedup vs baseline: 1.2685x; 1.2685x over previous
//
#include <hip/hip_runtime.h>
#include <hip/hip_bf16.h>

typedef float f32x4 __attribute__((ext_vector_type(4)));

#define M_DIM   500000
#define NPER    21
#define NELEM   (M_DIM * NPER)          // 10,500,000 floats per (tensor, group)
#define NF4     (NELEM / 4)             // 2,625,000 float4 units
#define NBX     256
#define TPB     252
#define CH      2                        // float4s per thread-chunk (32 B contiguous)
#define STR_F4  (NBX * TPB * CH)         // 129,024 f4s per grid pass
#define DM      ((STR_F4 * 4) / 21)      // 24,576 (pass stride divisible by 21)
#define P_FULL  20                       // passes 0..19 fully in-bounds for every thread

__device__ __forceinline__ float sig_fast(float st, float k1, float k0) {
    // sigmoid(B*(base+st)) = 1/(1+2^(k1*st+k0)),  k1=-B*log2e, k0=k1*base
    return __builtin_amdgcn_rcpf(1.0f + __builtin_amdgcn_exp2f(fmaf(st, k1, k0)));
}

__global__ __launch_bounds__(TPB) void probs_reduce_kernel(
    const float* __restrict__ ST0, const float* __restrict__ W0,
    const float* __restrict__ ST1, const float* __restrict__ W1,
    const float* __restrict__ BEV, const float* __restrict__ BEVp,
    const float* __restrict__ Bp, float* __restrict__ partial)
{
    const int t   = threadIdx.x;
    const int tau = blockIdx.y >> 2;   // 0: (ST0,W0)  1: (ST1,W1)
    const int grp = blockIdx.y & 3;

    const float* __restrict__ ST = (tau == 0 ? ST0 : ST1) + grp * M_DIM;
    const float* __restrict__ Wg = (tau == 0 ? W0 : W1) + (size_t)grp * NELEM;

    const float B    = Bp[0];
    const float base = fmaxf(BEVp[0], 0.0f) * BEV[0];
    const float k1   = -B * 1.44269504f;
    const float k0   = k1 * base;

    int c0 = (blockIdx.x * TPB + t) * CH;        // f4 index of this thread's chunk
    const int e0 = c0 * 4;
    int m = (int)((unsigned)e0 / 21u);
    const int cthr = 21 - (e0 - m * 21);         // j < cthr use sig(m), else sig(m+1)

    float a0=0.f,a1=0.f,a2=0.f,a3=0.f,a4=0.f,a5=0.f,a6=0.f,a7=0.f;

#define BODY()                                                          \
    {                                                                   \
        const f32x4* wp = (const f32x4*)(Wg + (size_t)c0 * 4);          \
        const f32x4 wA = wp[0];                                         \
        const f32x4 wB = wp[1];                                         \
        const int   mp = (m + 1 < M_DIM) ? m + 1 : M_DIM - 1;           \
        const float g0 = sig_fast(ST[m],  k1, k0);                      \
        const float g1 = sig_fast(ST[mp], k1, k0);                      \
        a0 = fmaf(wA[0], g0, a0);                                       \
        a1 = fmaf(wA[1], (1 < cthr) ? g0 : g1, a1);                     \
        a2 = fmaf(wA[2], (2 < cthr) ? g0 : g1, a2);                     \
        a3 = fmaf(wA[3], (3 < cthr) ? g0 : g1, a3);                     \
        a4 = fmaf(wB[0], (4 < cthr) ? g0 : g1, a4);                     \
        a5 = fmaf(wB[1], (5 < cthr) ? g0 : g1, a5);                     \
        a6 = fmaf(wB[2], (6 < cthr) ? g0 : g1, a6);                     \
        a7 = fmaf(wB[3], (7 < cthr) ? g0 : g1, a7);                     \
    }

    #pragma unroll 1
    for (int p = 0; p < P_FULL; ++p) {
        BODY();
        c0 += STR_F4; m += DM;
    }
    if (c0 < NF4) {                               // tail pass: chunk fully in or out
        BODY();
    }
#undef BODY

    // element (t, j) has residue (8t + j) % 21; 2016 % 21 == 0 so LDS idx % 21 works
    __shared__ float sm[TPB * 8];
    sm[t*8+0]=a0; sm[t*8+1]=a1; sm[t*8+2]=a2; sm[t*8+3]=a3;
    sm[t*8+4]=a4; sm[t*8+5]=a5; sm[t*8+6]=a6; sm[t*8+7]=a7;
    __syncthreads();

    if (t < NPER) {
        float s = 0.f;
        #pragma unroll
        for (int q = 0; q < (TPB * 8) / NPER; ++q)   // 96 entries per residue
            s += sm[t + NPER * q];
        partial[(blockIdx.y * NBX + blockIdx.x) * NPER + t] = s;   // no atomics, no memset
    }
}

__global__ __launch_bounds__(256) void probs_final_kernel(
    const float* __restrict__ partial,   // (8, NBX, 21)
    const float* __restrict__ pp,        // (5,4)
    float* __restrict__ out)
{
    __shared__ float tmpL[168];          // (8,21): y*21+p
    __shared__ float red[256];
    const int t = threadIdx.x;

    if (t < 168) {
        const int y = t / NPER, p = t % NPER;
        float s = 0.f;
        #pragma unroll 4
        for (int bx = 0; bx < NBX; ++bx)
            s += partial[(y * NBX + bx) * NPER + p];
        tmpL[y * NPER + p] = s;
    }
    __syncthreads();

    float val = 0.f;
    if (t < 84) {
        const int i = t / 21, inner = t % 21;
        float Pk[5];
        #pragma unroll
        for (int k = 0; k < 5; ++k) {
            float a0 = pp[k*4+0], a1 = pp[k*4+1], a2 = pp[k*4+2], a3 = pp[k*4+3];
            float mx = fmaxf(fmaxf(a0, a1), fmaxf(a2, a3));
            float e0 = __expf(a0-mx), e1 = __expf(a1-mx), e2 = __expf(a2-mx), e3 = __expf(a3-mx);
            float inv = 1.0f / (e0 + e1 + e2 + e3);
            float q[4] = {e0*inv, e1*inv, e2*inv, e3*inv};
            float v = q[i];
            if (inner > 0) {
                int jj = (inner - 1) / 5, kk = (inner - 1) % 5;
                v *= q[jj];
                if (kk > 0) v *= q[kk - 1];
            }
            Pk[k] = v;
        }
        float t0 = tmpL[t], t1 = tmpL[84 + t];
        val = Pk[0] * t0 + (Pk[1] + Pk[2] + Pk[3] + Pk[4]) * t1;
    }
    red[t] = val;
    __syncthreads();
    #pragma unroll
    for (int s = 128; s > 0; s >>= 1) {
        if (t < s) red[t] += red[t + s];
        __syncthreads();
    }
    if (t == 0) out[0] = red[0] * 0.2f;   // mean over 5 outs
}

extern "C" void kernel_launch(void* const* d_in, const int* in_sizes, int n_in,
                              void* d_out, int out_size, void* d_ws, size_t ws_size,
                              hipStream_t stream) {
    const float* BEV  = (const float*)d_in[0];
    const float* ST0  = (const float*)d_in[1];
    const float* W0   = (const float*)d_in[2];
    const float* ST1  = (const float*)d_in[3];
    const float* W1   = (const float*)d_in[4];
    const float* pp   = (const float*)d_in[5];
    const float* BEVp = (const float*)d_in[6];
    const float* B    = (const float*)d_in[7];
    float* out = (float*)d_out;
    float* partial = (float*)d_ws;   // 8*NBX*21 = 43,008 floats (172 KB), fully overwritten

    probs_reduce_kernel<<<dim3(NBX, 8), TPB, 0, stream>>>(ST0, W0, ST1, W1,
                                                          BEV, BEVp, B, partial);
    probs_final_kernel<<<1, 256, 0, stream>>>(partial, pp, out);
}

// Round 8
// 70.527 us; speedup vs baseline: 1.5739x; 1.2408x over previous
//
#include <hip/hip_runtime.h>
#include <hip/hip_bf16.h>

typedef float f32x4 __attribute__((ext_vector_type(4)));

#define M_DIM   500000
#define NPER    21
#define NELEM   (M_DIM * NPER)          // 10,500,000 floats per (tensor, group)
#define NF4     (NELEM / 4)             // 2,625,000 float4 units
#define NBLK    256
#define TPB     252
#define CH      2                        // float4s per thread-chunk (32 B contiguous)
#define STR_F4  (NBLK * TPB * CH)        // 129,024 f4s per grid pass
#define DM      ((STR_F4 * 4) / 21)      // 24,576 (pass stride divisible by 21)
#define P_PIN   12                       // passes 0..11: normal loads (LLC-resident region)
#define P_FULL  20                       // passes 0..19 fully in-bounds for every thread

__device__ __forceinline__ float sig_fast(float st, float k1, float k0) {
    // sigmoid(B*(base+st)) = 1/(1+2^(k1*st+k0)),  k1=-B*log2e, k0=k1*base
    return __builtin_amdgcn_rcpf(1.0f + __builtin_amdgcn_exp2f(fmaf(st, k1, k0)));
}

__global__ __launch_bounds__(TPB) void probs_reduce_kernel(
    const float* __restrict__ ST0, const float* __restrict__ W0,
    const float* __restrict__ ST1, const float* __restrict__ W1,
    const float* __restrict__ BEV, const float* __restrict__ BEVp,
    const float* __restrict__ Bp, float* __restrict__ tmp)
{
    const int t   = threadIdx.x;
    const int tau = blockIdx.y >> 2;   // 0: (ST0,W0)  1: (ST1,W1)
    const int grp = blockIdx.y & 3;

    const float* __restrict__ ST = (tau == 0 ? ST0 : ST1) + grp * M_DIM;
    const float* __restrict__ Wg = (tau == 0 ? W0 : W1) + (size_t)grp * NELEM;

    const float B    = Bp[0];
    const float base = fmaxf(BEVp[0], 0.0f) * BEV[0];
    const float k1   = -B * 1.44269504f;
    const float k0   = k1 * base;

    int c0 = (blockIdx.x * TPB + t) * CH;        // f4 index of this thread's chunk
    const int e0 = c0 * 4;
    int m = (int)((unsigned)e0 / 21u);
    const int cthr = 21 - (e0 - m * 21);         // j < cthr use sig(m), else sig(m+1)

    float a0=0.f,a1=0.f,a2=0.f,a3=0.f,a4=0.f,a5=0.f,a6=0.f,a7=0.f;

#define BODY(LOADA, LOADB)                                              \
    {                                                                   \
        const f32x4 wA = LOADA;                                         \
        const f32x4 wB = LOADB;                                         \
        const int   mp = (m + 1 < M_DIM) ? m + 1 : M_DIM - 1;           \
        const float g0 = sig_fast(ST[m],  k1, k0);                      \
        const float g1 = sig_fast(ST[mp], k1, k0);                      \
        a0 = fmaf(wA[0], g0, a0);                                       \
        a1 = fmaf(wA[1], (1 < cthr) ? g0 : g1, a1);                     \
        a2 = fmaf(wA[2], (2 < cthr) ? g0 : g1, a2);                     \
        a3 = fmaf(wA[3], (3 < cthr) ? g0 : g1, a3);                     \
        a4 = fmaf(wB[0], (4 < cthr) ? g0 : g1, a4);                     \
        a5 = fmaf(wB[1], (5 < cthr) ? g0 : g1, a5);                     \
        a6 = fmaf(wB[2], (6 < cthr) ? g0 : g1, a6);                     \
        a7 = fmaf(wB[3], (7 < cthr) ? g0 : g1, a7);                     \
    }

    // ---- passes 0..P_PIN-1: normal loads; this ~198MB region stays LLC-resident ----
    #pragma unroll 1
    for (int p = 0; p < P_PIN; ++p) {
        const f32x4* wp = (const f32x4*)(Wg + (size_t)c0 * 4);
        BODY(wp[0], wp[1]);
        c0 += STR_F4; m += DM;
    }
    // ---- passes P_PIN..P_FULL-1: non-temporal -> stream from HBM ----
    #pragma unroll 1
    for (int p = P_PIN; p < P_FULL; ++p) {
        const f32x4* wp = (const f32x4*)(Wg + (size_t)c0 * 4);
        BODY(__builtin_nontemporal_load(wp), __builtin_nontemporal_load(wp + 1));
        c0 += STR_F4; m += DM;
    }
    // ---- tail pass (chunk-aligned: fully in or fully out) ----
    if (c0 < NF4) {
        const f32x4* wp = (const f32x4*)(Wg + (size_t)c0 * 4);
        BODY(__builtin_nontemporal_load(wp), __builtin_nontemporal_load(wp + 1));
    }
#undef BODY

    // element (t, j) has residue (8t + j) % 21; 2016 % 21 == 0 so LDS idx % 21 works
    __shared__ float sm[TPB * 8];
    sm[t*8+0]=a0; sm[t*8+1]=a1; sm[t*8+2]=a2; sm[t*8+3]=a3;
    sm[t*8+4]=a4; sm[t*8+5]=a5; sm[t*8+6]=a6; sm[t*8+7]=a7;
    __syncthreads();

    if (t < NPER) {
        float s = 0.f;
        #pragma unroll
        for (int q = 0; q < (TPB * 8) / NPER; ++q)   // 96 entries per residue
            s += sm[t + NPER * q];
        atomicAdd(&tmp[blockIdx.y * NPER + t], s);
    }
}

__global__ void probs_final_kernel(const float* __restrict__ tmp,
                                   const float* __restrict__ pp,   // (5,4)
                                   float* __restrict__ out)
{
    __shared__ float red[128];
    const int t = threadIdx.x;
    float val = 0.f;
    if (t < 84) {
        const int i = t / 21, inner = t % 21;
        float Pk[5];
        #pragma unroll
        for (int k = 0; k < 5; ++k) {
            float a0 = pp[k*4+0], a1 = pp[k*4+1], a2 = pp[k*4+2], a3 = pp[k*4+3];
            float mx = fmaxf(fmaxf(a0, a1), fmaxf(a2, a3));
            float e0 = __expf(a0-mx), e1 = __expf(a1-mx), e2 = __expf(a2-mx), e3 = __expf(a3-mx);
            float inv = 1.0f / (e0 + e1 + e2 + e3);
            float q[4] = {e0*inv, e1*inv, e2*inv, e3*inv};
            float v = q[i];
            if (inner > 0) {
                int jj = (inner - 1) / 5, kk = (inner - 1) % 5;
                v *= q[jj];
                if (kk > 0) v *= q[kk - 1];
            }
            Pk[k] = v;
        }
        float t0 = tmp[t], t1 = tmp[84 + t];
        val = Pk[0] * t0 + (Pk[1] + Pk[2] + Pk[3] + Pk[4]) * t1;
    }
    red[t] = val;
    __syncthreads();
    #pragma unroll
    for (int s = 64; s > 0; s >>= 1) {
        if (t < s) red[t] += red[t + s];
        __syncthreads();
    }
    if (t == 0) out[0] = red[0] * 0.2f;   // mean over 5 outs
}

extern "C" void kernel_launch(void* const* d_in, const int* in_sizes, int n_in,
                              void* d_out, int out_size, void* d_ws, size_t ws_size,
                              hipStream_t stream) {
    const float* BEV  = (const float*)d_in[0];
    const float* ST0  = (const float*)d_in[1];
    const float* W0   = (const float*)d_in[2];
    const float* ST1  = (const float*)d_in[3];
    const float* W1   = (const float*)d_in[4];
    const float* pp   = (const float*)d_in[5];
    const float* BEVp = (const float*)d_in[6];
    const float* B    = (const float*)d_in[7];
    float* out = (float*)d_out;
    float* tmp = (float*)d_ws;   // 168 floats: tmp0[84] then tmp1[84]

    hipMemsetAsync(tmp, 0, 168 * sizeof(float), stream);
    probs_reduce_kernel<<<dim3(NBLK, 8), TPB, 0, stream>>>(ST0, W0, ST1, W1,
                                                           BEV, BEVp, B, tmp);
    probs_final_kernel<<<1, 128, 0, stream>>>(tmp, pp, out);
}